// Round 17
// baseline (46.871 us; speedup 1.0000x reference)
//
#include <hip/hip_runtime.h>

// Chamfer NN squared distances via MFMA (f16 hi/lo emulation).
// Round-17: clean 8-waves/SIMD test of the R11 loop.
//   - R11's waves_per_eu(4,4) CAPPED occupancy at 4 waves/EU (52-VGPR loop
//     could have run 8). R16's test was confounded (waves_per_eu(8) min-pin
//     + staging on waves 0-1 only). This round: NO waves_per_eu attr
//     (natural ~52 VGPR -> 8 waves/SIMD allowed), CHUNK=256 (16 KB LDS),
//     SPLIT=2 (grid 2048 = 8 blocks/CU), wave-balanced staging.
//
// d(q,r) = |q|^2 + |r|^2 - 2 q.r in ONE mfma_f32_32x32x16_f16 (13 K-slots):
//   A (query row, g=0): {-2hx,-2hy,-2hz,-2hx,-2hy,-2hz,-2lx,-2ly}
//   A (query row, g=1): {-2lz, 1, 1, sh, sl, 0, 0, 0}
//   B (ref col,   g=0): { hx,  hy,  hz,  lx,  ly,  lz, hx, hy}
//   B (ref col,   g=1): { hz,  sh,  sl,  1,  1, 0, 0, 0}
// => D = squared distance (error ~1e-4 vs 0.12 threshold).
//
// Per chunk (256 refs, 2x4KB double-buffer): wave w's lanes 0-31 issue the
// global loads for its 64-pt slice of chunk t+1 (T14, flies under compute)
// -> compute buf[cur] (4 pair-steps: 2 ds_read_b128, 2 MFMA, 16 fmin-folds)
// -> pack+ds_write buf[cur^1] -> one barrier. SPLIT partials combined via
// atomicMin on the int view (memset 0x7f first; 262K 2-way atomics, cheap).

typedef _Float16 v8h  __attribute__((ext_vector_type(8)));
typedef float    v16f __attribute__((ext_vector_type(16)));

constexpr int TPB   = 256;        // 4 waves
constexpr int RPW   = 32;         // rows per wave (1 A-fragment)
constexpr int RPB   = 4 * RPW;    // 128 rows per block
constexpr int CHUNK = 256;        // refs per buffer (2 halves x 4 KB)
constexpr int SPLIT = 2;          // ref-dim split -> 2048 blocks = 8/CU

__device__ __forceinline__ void split3(float x, float y, float z,
    _Float16& hx, _Float16& hy, _Float16& hz,
    _Float16& lx, _Float16& ly, _Float16& lz,
    _Float16& sh, _Float16& sl)
{
    const float s = fmaf(z, z, fmaf(y, y, x * x));
    hx = (_Float16)x; hy = (_Float16)y; hz = (_Float16)z;
    lx = (_Float16)(x - (float)hx);
    ly = (_Float16)(y - (float)hy);
    lz = (_Float16)(z - (float)hz);
    sh = (_Float16)s;
    sl = (_Float16)(s - (float)sh);
}

__device__ __forceinline__ v8h packA(const float* __restrict__ qb, int row, int g)
{
    const float x = qb[(size_t)row * 3 + 0];
    const float y = qb[(size_t)row * 3 + 1];
    const float z = qb[(size_t)row * 3 + 2];
    _Float16 hx, hy, hz, lx, ly, lz, sh, sl;
    split3(x, y, z, hx, hy, hz, lx, ly, lz, sh, sl);
    const _Float16 nhx = (_Float16)(-2.f * x);
    const _Float16 nhy = (_Float16)(-2.f * y);
    const _Float16 nhz = (_Float16)(-2.f * z);
    const _Float16 nlx = (_Float16)(-2.f * (float)lx);
    const _Float16 nly = (_Float16)(-2.f * (float)ly);
    const _Float16 nlz = (_Float16)(-2.f * (float)lz);
    const _Float16 one = (_Float16)1.f, zz = (_Float16)0.f;
    const v8h A0 = {nhx, nhy, nhz, nhx, nhy, nhz, nlx, nly};
    const v8h A1 = {nlz, one, one, sh, sl, zz, zz, zz};
    return g ? A1 : A0;
}

__device__ __forceinline__ void packB(float x, float y, float z, uint4& h0, uint4& h1)
{
    _Float16 hx, hy, hz, lx, ly, lz, sh, sl;
    split3(x, y, z, hx, hy, hz, lx, ly, lz, sh, sl);
    const _Float16 one = (_Float16)1.f, zz = (_Float16)0.f;
    const v8h B0 = {hx, hy, hz, lx, ly, lz, hx, hy};
    const v8h B1 = {hz, sh, sl, one, one, zz, zz, zz};
    h0 = __builtin_bit_cast(uint4, B0);
    h1 = __builtin_bit_cast(uint4, B1);
}

__global__ __launch_bounds__(TPB)
void nnd_mfma10(
    const float* __restrict__ p1, const float* __restrict__ p2,
    float* __restrict__ out, int B, int N, int M)
{
    const int dir = blockIdx.z >> 1;     // 0: q=p1,r=p2 (dist1); 1: swapped
    const int s   = blockIdx.z & 1;      // ref-dim split index
    const int b   = blockIdx.y;
    const float* __restrict__ q = dir ? p2 : p1;
    const float* __restrict__ r = dir ? p1 : p2;
    const int Nq = dir ? M : N;
    const int Nr = dir ? N : M;
    float* __restrict__ o = out + (dir ? (size_t)B * N : 0) + (size_t)b * Nq;

    const int tid  = threadIdx.x;
    const int w    = tid >> 6;
    const int lane = tid & 63;
    const int c    = lane & 31;          // MFMA row (A) / col (B) within tile
    const int g    = lane >> 5;          // k-half
    const int row0 = blockIdx.x * RPB + w * RPW;
    const bool stager = (g == 0);        // lanes 0-31 of each wave stage

    const float* qb = q + (size_t)b * Nq * 3;
    const v8h a = packA(qb, row0 + c, g);

    v16f zc;
#pragma unroll
    for (int i = 0; i < 16; ++i) zc[i] = 0.f;
    float rm[16];
#pragma unroll
    for (int i = 0; i < 16; ++i) rm[i] = 3.0e38f;

    __shared__ uint4 sb[2][2 * CHUNK];   // [buf][half*CHUNK + slot]
    const float* rb = r + (size_t)b * Nr * 3;
    const int r0 = s * (Nr / SPLIT);
    const int NT = (Nr / SPLIT) / CHUNK;

    // wave-balanced staging: wave w owns pts [w*64, w*64+64) of each chunk;
    // active lanes c=0..31 load 2 pts each (3 float2 = coalesced 256B/group).
    const int pbase = w * 64 + 2 * c;    // pt slot for this lane (k=0,1)

    // ---- prologue: stage chunk 0 into buf 0 ----
    if (stager) {
        const float2* s2 = (const float2*)(rb + (size_t)(r0 + w * 64) * 3);
        const float2 A  = s2[3 * c + 0];
        const float2 C2 = s2[3 * c + 1];
        const float2 E  = s2[3 * c + 2];
        uint4 h00, h01, h10, h11;
        packB(A.x, A.y, C2.x, h00, h01);
        packB(C2.y, E.x, E.y, h10, h11);
        sb[0][pbase]             = h00;
        sb[0][pbase + 1]         = h10;
        sb[0][CHUNK + pbase]     = h01;
        sb[0][CHUNK + pbase + 1] = h11;
    }
    __syncthreads();

    int cur = 0;
    for (int t = 0; t < NT; ++t) {
        const bool more = (t + 1 < NT);
        // (1) issue global loads for chunk t+1 (fly under compute)
        float2 A, C2, E;
        if (more && stager) {
            const float2* s2 = (const float2*)(rb + (size_t)(r0 + (t + 1) * CHUNK + w * 64) * 3);
            A  = s2[3 * c + 0];
            C2 = s2[3 * c + 1];
            E  = s2[3 * c + 2];
        }
        // (2) compute on buf[cur]: 4 pair-steps (2 ds_read, 2 MFMA, 16 folds)
        const uint4* sbase = &sb[cur][g * CHUNK];
#pragma unroll 2
        for (int st = 0; st < CHUNK / 32; st += 2) {
            const v8h bfA = __builtin_bit_cast(v8h, sbase[st * 32 + c]);
            const v8h bfB = __builtin_bit_cast(v8h, sbase[st * 32 + 32 + c]);
            const v16f da = __builtin_amdgcn_mfma_f32_32x32x16_f16(a, bfA, zc, 0, 0, 0);
            const v16f db = __builtin_amdgcn_mfma_f32_32x32x16_f16(a, bfB, zc, 0, 0, 0);
#pragma unroll
            for (int i = 0; i < 16; ++i)
                rm[i] = fminf(fminf(da[i], db[i]), rm[i]);
        }
        // (3) pack + write chunk t+1 into buf[cur^1]
        if (more) {
            if (stager) {
                uint4 h00, h01, h10, h11;
                packB(A.x, A.y, C2.x, h00, h01);
                packB(C2.y, E.x, E.y, h10, h11);
                uint4* d = sb[cur ^ 1];
                d[pbase]             = h00;
                d[pbase + 1]         = h10;
                d[CHUNK + pbase]     = h01;
                d[CHUNK + pbase + 1] = h11;
            }
            __syncthreads();             // writes visible before next compute
        }
        cur ^= 1;
    }

    // ---- epilogue: min over the 32 columns (bits 0-4), atomicMin combine ----
#pragma unroll
    for (int i = 0; i < 16; ++i) {
        float v = rm[i];
        v = fminf(v, __shfl_xor(v, 1));
        v = fminf(v, __shfl_xor(v, 2));
        v = fminf(v, __shfl_xor(v, 4));
        v = fminf(v, __shfl_xor(v, 8));
        v = fminf(v, __shfl_xor(v, 16));
        rm[i] = v;
    }
    if (c == 0) {
#pragma unroll
        for (int i = 0; i < 16; ++i) {
            const int rr = (i & 3) + 8 * (i >> 2) + 4 * g;  // verified C layout
            atomicMin((int*)&o[row0 + rr], __float_as_int(rm[i]));
        }
    }
}

// ---------------- fallback: round-3 identity-folded VALU kernel ----------------
constexpr int FTPB   = 256;
constexpr int FIPT   = 4;
constexpr int FTILE  = 512;
constexpr int FSPLIT = 8;

__global__ __launch_bounds__(FTPB, 4) void nnd_fold(
    const float* __restrict__ p1, const float* __restrict__ p2,
    float* __restrict__ out, int B, int N, int M)
{
    const int z   = blockIdx.z;
    const int dir = z / FSPLIT;
    const int s   = z % FSPLIT;
    const int b   = blockIdx.y;

    const float* __restrict__ q = dir ? p2 : p1;
    const float* __restrict__ r = dir ? p1 : p2;
    const int Nq = dir ? M : N;
    const int Nr = dir ? N : M;
    float* __restrict__ o = out + (dir ? (size_t)B * N : 0) + (size_t)b * Nq;

    const int tid = threadIdx.x;
    const float* qb = q + (size_t)b * Nq * 3;
    float qx[FIPT], qy[FIPT], qz[FIPT], qs[FIPT], mn[FIPT];
    int   qi[FIPT];
#pragma unroll
    for (int i = 0; i < FIPT; ++i) {
        qi[i] = blockIdx.x * (FTPB * FIPT) + i * FTPB + tid;
        if (qi[i] < Nq) {
            qx[i] = qb[qi[i] * 3 + 0]; qy[i] = qb[qi[i] * 3 + 1]; qz[i] = qb[qi[i] * 3 + 2];
        } else { qx[i] = qy[i] = qz[i] = 0.f; }
        float sq = qx[i] * qx[i];
        sq = fmaf(qy[i], qy[i], sq); sq = fmaf(qz[i], qz[i], sq);
        qs[i] = sq; mn[i] = 3.0e38f;
    }
    const int per = (Nr + FSPLIT - 1) / FSPLIT;
    const int r0 = s * per, r1 = min(Nr, r0 + per);
    __shared__ float4 shm[FTILE];
    const float* rb = r + (size_t)b * Nr * 3;
    for (int ts = r0; ts < r1; ts += FTILE) {
        const int npts = min(FTILE, r1 - ts);
        __syncthreads();
        if (npts == FTILE && ((((size_t)b * Nr + (size_t)ts) * 3) & 1) == 0) {
            const float2* src = (const float2*)(rb + (size_t)ts * 3);
            float2 a = src[3 * tid + 0], c2 = src[3 * tid + 1], e = src[3 * tid + 2];
            float s0 = a.x * a.x; s0 = fmaf(a.y, a.y, s0); s0 = fmaf(c2.x, c2.x, s0);
            float s1 = c2.y * c2.y; s1 = fmaf(e.x, e.x, s1); s1 = fmaf(e.y, e.y, s1);
            shm[2 * tid + 0] = make_float4(-2.f * a.x, -2.f * a.y, -2.f * c2.x, s0);
            shm[2 * tid + 1] = make_float4(-2.f * c2.y, -2.f * e.x, -2.f * e.y, s1);
        } else {
#pragma unroll
            for (int k = 0; k < 2; ++k) {
                const int pl = 2 * tid + k;
                float4 v = make_float4(0.f, 0.f, 0.f, 3.0e38f);
                if (pl < npts) {
                    const float* pp = rb + (size_t)(ts + pl) * 3;
                    float sq = pp[0] * pp[0];
                    sq = fmaf(pp[1], pp[1], sq); sq = fmaf(pp[2], pp[2], sq);
                    v = make_float4(-2.f * pp[0], -2.f * pp[1], -2.f * pp[2], sq);
                }
                shm[pl] = v;
            }
        }
        __syncthreads();
#pragma unroll 8
        for (int j = 0; j < FTILE; ++j) {
            const float4 p = shm[j];
#pragma unroll
            for (int i = 0; i < FIPT; ++i) {
                float t = fmaf(p.x, qx[i], p.w);
                t = fmaf(p.y, qy[i], t);
                t = fmaf(p.z, qz[i], t);
                mn[i] = fminf(mn[i], t);
            }
        }
    }
#pragma unroll
    for (int i = 0; i < FIPT; ++i)
        if (qi[i] < Nq) atomicMin((int*)&o[qi[i]], __float_as_int(mn[i] + qs[i]));
}

extern "C" void kernel_launch(void* const* d_in, const int* in_sizes, int n_in,
                              void* d_out, int out_size, void* d_ws, size_t ws_size,
                              hipStream_t stream) {
    const float* p1 = (const float*)d_in[0];
    const float* p2 = (const float*)d_in[1];
    float* out = (float*)d_out;

    const int B = 16;
    const int N = in_sizes[0] / (B * 3);
    const int M = in_sizes[1] / (B * 3);

    // init outputs to large positive float (0x7f7f7f7f ~ 3.39e38) for atomicMin
    hipMemsetAsync(d_out, 0x7f, (size_t)out_size * sizeof(float), stream);

    const bool mfma_ok = (N == M) && (N % RPB == 0) && ((N / SPLIT) % CHUNK == 0);

    if (mfma_ok) {
        dim3 grid(N / RPB, B, 2 * SPLIT);   // 2048 blocks = 8 blocks/CU
        nnd_mfma10<<<grid, TPB, 0, stream>>>(p1, p2, out, B, N, M);
    } else {
        const int qmax = (N > M) ? N : M;
        dim3 grid((qmax + FTPB * FIPT - 1) / (FTPB * FIPT), B, 2 * FSPLIT);
        nnd_fold<<<grid, FTPB, 0, stream>>>(p1, p2, out, B, N, M);
    }
}

// Round 18
// 34.414 us; speedup vs baseline: 1.3620x; 1.3620x over previous
//
#include <hip/hip_runtime.h>

// Chamfer NN squared distances via MFMA (f16 hi/lo emulation).
// Round-18: R11's fused structure + 2 A-frags/wave to HALVE the DS pipe.
//
// Corrected pipe model (R17): MFMA 32x32x16 = 8 cyc -> matrix pipe is only
// ~1.7us total; the binding pipe in R11 is per-CU LDS: 16 waves x 128
// ds_read_b128 x 12cyc ~ 10.2us + writes 2.6 ~ 12.8us/CU of a 23us kernel.
// Fix: RPW=64 (A-frags a0,a1) -> each ds_read feeds 2 MFMAs (reads halve);
// RPB=256 + SPLIT=2 over refs -> each block stages Nr/2 (pack VALU and
// ds_write halve). Grid 1024 = 4 blocks/CU. Inner loop = R15's (proven).
//
// d(q,r) = |q|^2 + |r|^2 - 2 q.r in ONE mfma_f32_32x32x16_f16 (13 K-slots):
//   A (query row, g=0): {-2hx,-2hy,-2hz,-2hx,-2hy,-2hz,-2lx,-2ly}
//   A (query row, g=1): {-2lz, 1, 1, sh, sl, 0, 0, 0}
//   B (ref col,   g=0): { hx,  hy,  hz,  lx,  ly,  lz, hx, hy}
//   B (ref col,   g=1): { hz,  sh,  sl,  1,  1, 0, 0, 0}
// => D = squared distance (error ~1e-4 vs 0.12 threshold).
//
// Staging = R11's conflict-free layout (256 threads x 2 pts, consecutive
// 16B slots; R17's w*64+2c layout was 8-way write-conflicted - reverted).
// waves_per_eu(4,4) pins the 128-VGPR budget (~100 live; R6/R13 spill trap).
// SPLIT partials via atomicMin on int view (memset 0x7f; 524K 2-way atomics).

typedef _Float16 v8h  __attribute__((ext_vector_type(8)));
typedef float    v16f __attribute__((ext_vector_type(16)));

constexpr int TPB   = 256;        // 4 waves
constexpr int RPW   = 64;         // rows per wave (2 A-fragments)
constexpr int RPB   = 4 * RPW;    // 256 rows per block
constexpr int CHUNK = 512;        // refs per buffer (2 halves x 8 KB = 16 KB)
constexpr int SPLIT = 2;          // ref-dim split -> 1024 blocks = 4/CU

__device__ __forceinline__ void split3(float x, float y, float z,
    _Float16& hx, _Float16& hy, _Float16& hz,
    _Float16& lx, _Float16& ly, _Float16& lz,
    _Float16& sh, _Float16& sl)
{
    const float s = fmaf(z, z, fmaf(y, y, x * x));
    hx = (_Float16)x; hy = (_Float16)y; hz = (_Float16)z;
    lx = (_Float16)(x - (float)hx);
    ly = (_Float16)(y - (float)hy);
    lz = (_Float16)(z - (float)hz);
    sh = (_Float16)s;
    sl = (_Float16)(s - (float)sh);
}

__device__ __forceinline__ v8h packA(const float* __restrict__ qb, int row, int g)
{
    const float x = qb[(size_t)row * 3 + 0];
    const float y = qb[(size_t)row * 3 + 1];
    const float z = qb[(size_t)row * 3 + 2];
    _Float16 hx, hy, hz, lx, ly, lz, sh, sl;
    split3(x, y, z, hx, hy, hz, lx, ly, lz, sh, sl);
    const _Float16 nhx = (_Float16)(-2.f * x);
    const _Float16 nhy = (_Float16)(-2.f * y);
    const _Float16 nhz = (_Float16)(-2.f * z);
    const _Float16 nlx = (_Float16)(-2.f * (float)lx);
    const _Float16 nly = (_Float16)(-2.f * (float)ly);
    const _Float16 nlz = (_Float16)(-2.f * (float)lz);
    const _Float16 one = (_Float16)1.f, zz = (_Float16)0.f;
    const v8h A0 = {nhx, nhy, nhz, nhx, nhy, nhz, nlx, nly};
    const v8h A1 = {nlz, one, one, sh, sl, zz, zz, zz};
    return g ? A1 : A0;
}

__device__ __forceinline__ void packB(float x, float y, float z, uint4& h0, uint4& h1)
{
    _Float16 hx, hy, hz, lx, ly, lz, sh, sl;
    split3(x, y, z, hx, hy, hz, lx, ly, lz, sh, sl);
    const _Float16 one = (_Float16)1.f, zz = (_Float16)0.f;
    const v8h B0 = {hx, hy, hz, lx, ly, lz, hx, hy};
    const v8h B1 = {hz, sh, sl, one, one, zz, zz, zz};
    h0 = __builtin_bit_cast(uint4, B0);
    h1 = __builtin_bit_cast(uint4, B1);
}

__global__ __launch_bounds__(TPB)
__attribute__((amdgpu_waves_per_eu(4, 4)))
void nnd_mfma11(
    const float* __restrict__ p1, const float* __restrict__ p2,
    float* __restrict__ out, int B, int N, int M)
{
    const int dir = blockIdx.z >> 1;     // 0: q=p1,r=p2 (dist1); 1: swapped
    const int s   = blockIdx.z & 1;      // ref-dim split index
    const int b   = blockIdx.y;
    const float* __restrict__ q = dir ? p2 : p1;
    const float* __restrict__ r = dir ? p1 : p2;
    const int Nq = dir ? M : N;
    const int Nr = dir ? N : M;
    float* __restrict__ o = out + (dir ? (size_t)B * N : 0) + (size_t)b * Nq;

    const int tid  = threadIdx.x;
    const int w    = tid >> 6;
    const int lane = tid & 63;
    const int c    = lane & 31;          // MFMA row (A) / col (B) within tile
    const int g    = lane >> 5;          // k-half
    const int row0 = blockIdx.x * RPB + w * RPW;

    const float* qb = q + (size_t)b * Nq * 3;
    const v8h a0 = packA(qb, row0 + c, g);
    const v8h a1 = packA(qb, row0 + 32 + c, g);

    v16f zc;
#pragma unroll
    for (int i = 0; i < 16; ++i) zc[i] = 0.f;
    float rm0[16], rm1[16];
#pragma unroll
    for (int i = 0; i < 16; ++i) { rm0[i] = 3.0e38f; rm1[i] = 3.0e38f; }

    __shared__ uint4 sb[2][2 * CHUNK];   // [buf][half*CHUNK + slot]
    const float* rb = r + (size_t)b * Nr * 3;
    const int r0 = s * (Nr / SPLIT);
    const int NT = (Nr / SPLIT) / CHUNK; // 4

    // ---- prologue: stage chunk 0 into buf 0 (R11 layout: conflict-free) ----
    {
        const float2* s2 = (const float2*)(rb + (size_t)r0 * 3);
        const float2 A  = s2[3 * tid + 0];
        const float2 C2 = s2[3 * tid + 1];
        const float2 E  = s2[3 * tid + 2];
        uint4 h00, h01, h10, h11;
        packB(A.x, A.y, C2.x, h00, h01);
        packB(C2.y, E.x, E.y, h10, h11);
        sb[0][tid]               = h00;
        sb[0][TPB + tid]         = h10;
        sb[0][CHUNK + tid]       = h01;
        sb[0][CHUNK + TPB + tid] = h11;
    }
    __syncthreads();

    int cur = 0;
    for (int t = 0; t < NT; ++t) {
        const bool more = (t + 1 < NT);
        // (1) issue global loads for chunk t+1 (fly under compute, T14)
        float2 A, C2, E;
        if (more) {
            const float2* s2 = (const float2*)(rb + (size_t)(r0 + (t + 1) * CHUNK) * 3);
            A  = s2[3 * tid + 0];
            C2 = s2[3 * tid + 1];
            E  = s2[3 * tid + 2];
        }
        // (2) compute on buf[cur]: 8 steps of 64 refs:
        //     2 ds_read_b128 -> 4 MFMA (2 per A-frag) -> 32 fmin-folds
        const uint4* sg = &sb[cur][g * CHUNK];
#pragma unroll 2
        for (int st = 0; st < CHUNK / 64; ++st) {
            const v8h bfA = __builtin_bit_cast(v8h, sg[st * 64 + c]);
            const v8h bfB = __builtin_bit_cast(v8h, sg[st * 64 + 32 + c]);
            const v16f da = __builtin_amdgcn_mfma_f32_32x32x16_f16(a0, bfA, zc, 0, 0, 0);
            const v16f db = __builtin_amdgcn_mfma_f32_32x32x16_f16(a0, bfB, zc, 0, 0, 0);
#pragma unroll
            for (int i = 0; i < 16; ++i)
                rm0[i] = fminf(fminf(da[i], db[i]), rm0[i]);
            const v16f dc = __builtin_amdgcn_mfma_f32_32x32x16_f16(a1, bfA, zc, 0, 0, 0);
            const v16f dd = __builtin_amdgcn_mfma_f32_32x32x16_f16(a1, bfB, zc, 0, 0, 0);
#pragma unroll
            for (int i = 0; i < 16; ++i)
                rm1[i] = fminf(fminf(dc[i], dd[i]), rm1[i]);
        }
        // (3) pack + write chunk t+1 into buf[cur^1]
        if (more) {
            uint4 h00, h01, h10, h11;
            packB(A.x, A.y, C2.x, h00, h01);
            packB(C2.y, E.x, E.y, h10, h11);
            uint4* d = sb[cur ^ 1];
            d[tid]               = h00;
            d[TPB + tid]         = h10;
            d[CHUNK + tid]       = h01;
            d[CHUNK + TPB + tid] = h11;
            __syncthreads();             // writes visible before next compute
        }
        cur ^= 1;
    }

    // ---- epilogue: min over the 32 columns (bits 0-4), atomicMin combine ----
#pragma unroll
    for (int i = 0; i < 16; ++i) {
        float v0 = rm0[i], v1 = rm1[i];
        v0 = fminf(v0, __shfl_xor(v0, 1));  v1 = fminf(v1, __shfl_xor(v1, 1));
        v0 = fminf(v0, __shfl_xor(v0, 2));  v1 = fminf(v1, __shfl_xor(v1, 2));
        v0 = fminf(v0, __shfl_xor(v0, 4));  v1 = fminf(v1, __shfl_xor(v1, 4));
        v0 = fminf(v0, __shfl_xor(v0, 8));  v1 = fminf(v1, __shfl_xor(v1, 8));
        v0 = fminf(v0, __shfl_xor(v0, 16)); v1 = fminf(v1, __shfl_xor(v1, 16));
        rm0[i] = v0; rm1[i] = v1;
    }
    if (c == 0) {
#pragma unroll
        for (int i = 0; i < 16; ++i) {
            const int rr = (i & 3) + 8 * (i >> 2) + 4 * g;  // verified C layout
            atomicMin((int*)&o[row0 + rr],      __float_as_int(rm0[i]));
            atomicMin((int*)&o[row0 + 32 + rr], __float_as_int(rm1[i]));
        }
    }
}

// ---------------- fallback: round-3 identity-folded VALU kernel ----------------
constexpr int FTPB   = 256;
constexpr int FIPT   = 4;
constexpr int FTILE  = 512;
constexpr int FSPLIT = 8;

__global__ __launch_bounds__(FTPB, 4) void nnd_fold(
    const float* __restrict__ p1, const float* __restrict__ p2,
    float* __restrict__ out, int B, int N, int M)
{
    const int z   = blockIdx.z;
    const int dir = z / FSPLIT;
    const int s   = z % FSPLIT;
    const int b   = blockIdx.y;

    const float* __restrict__ q = dir ? p2 : p1;
    const float* __restrict__ r = dir ? p1 : p2;
    const int Nq = dir ? M : N;
    const int Nr = dir ? N : M;
    float* __restrict__ o = out + (dir ? (size_t)B * N : 0) + (size_t)b * Nq;

    const int tid = threadIdx.x;
    const float* qb = q + (size_t)b * Nq * 3;
    float qx[FIPT], qy[FIPT], qz[FIPT], qs[FIPT], mn[FIPT];
    int   qi[FIPT];
#pragma unroll
    for (int i = 0; i < FIPT; ++i) {
        qi[i] = blockIdx.x * (FTPB * FIPT) + i * FTPB + tid;
        if (qi[i] < Nq) {
            qx[i] = qb[qi[i] * 3 + 0]; qy[i] = qb[qi[i] * 3 + 1]; qz[i] = qb[qi[i] * 3 + 2];
        } else { qx[i] = qy[i] = qz[i] = 0.f; }
        float sq = qx[i] * qx[i];
        sq = fmaf(qy[i], qy[i], sq); sq = fmaf(qz[i], qz[i], sq);
        qs[i] = sq; mn[i] = 3.0e38f;
    }
    const int per = (Nr + FSPLIT - 1) / FSPLIT;
    const int r0 = s * per, r1 = min(Nr, r0 + per);
    __shared__ float4 shm[FTILE];
    const float* rb = r + (size_t)b * Nr * 3;
    for (int ts = r0; ts < r1; ts += FTILE) {
        const int npts = min(FTILE, r1 - ts);
        __syncthreads();
        if (npts == FTILE && ((((size_t)b * Nr + (size_t)ts) * 3) & 1) == 0) {
            const float2* src = (const float2*)(rb + (size_t)ts * 3);
            float2 a = src[3 * tid + 0], c2 = src[3 * tid + 1], e = src[3 * tid + 2];
            float s0 = a.x * a.x; s0 = fmaf(a.y, a.y, s0); s0 = fmaf(c2.x, c2.x, s0);
            float s1 = c2.y * c2.y; s1 = fmaf(e.x, e.x, s1); s1 = fmaf(e.y, e.y, s1);
            shm[2 * tid + 0] = make_float4(-2.f * a.x, -2.f * a.y, -2.f * c2.x, s0);
            shm[2 * tid + 1] = make_float4(-2.f * c2.y, -2.f * e.x, -2.f * e.y, s1);
        } else {
#pragma unroll
            for (int k = 0; k < 2; ++k) {
                const int pl = 2 * tid + k;
                float4 v = make_float4(0.f, 0.f, 0.f, 3.0e38f);
                if (pl < npts) {
                    const float* pp = rb + (size_t)(ts + pl) * 3;
                    float sq = pp[0] * pp[0];
                    sq = fmaf(pp[1], pp[1], sq); sq = fmaf(pp[2], pp[2], sq);
                    v = make_float4(-2.f * pp[0], -2.f * pp[1], -2.f * pp[2], sq);
                }
                shm[pl] = v;
            }
        }
        __syncthreads();
#pragma unroll 8
        for (int j = 0; j < FTILE; ++j) {
            const float4 p = shm[j];
#pragma unroll
            for (int i = 0; i < FIPT; ++i) {
                float t = fmaf(p.x, qx[i], p.w);
                t = fmaf(p.y, qy[i], t);
                t = fmaf(p.z, qz[i], t);
                mn[i] = fminf(mn[i], t);
            }
        }
    }
#pragma unroll
    for (int i = 0; i < FIPT; ++i)
        if (qi[i] < Nq) atomicMin((int*)&o[qi[i]], __float_as_int(mn[i] + qs[i]));
}

extern "C" void kernel_launch(void* const* d_in, const int* in_sizes, int n_in,
                              void* d_out, int out_size, void* d_ws, size_t ws_size,
                              hipStream_t stream) {
    const float* p1 = (const float*)d_in[0];
    const float* p2 = (const float*)d_in[1];
    float* out = (float*)d_out;

    const int B = 16;
    const int N = in_sizes[0] / (B * 3);
    const int M = in_sizes[1] / (B * 3);

    // init outputs to large positive float (0x7f7f7f7f ~ 3.39e38) for atomicMin
    hipMemsetAsync(d_out, 0x7f, (size_t)out_size * sizeof(float), stream);

    const bool mfma_ok = (N == M) && (N % RPB == 0) && ((N / SPLIT) % CHUNK == 0);

    if (mfma_ok) {
        dim3 grid(N / RPB, B, 2 * SPLIT);   // (16, 16, 4) = 1024 blocks
        nnd_mfma11<<<grid, TPB, 0, stream>>>(p1, p2, out, B, N, M);
    } else {
        const int qmax = (N > M) ? N : M;
        dim3 grid((qmax + FTPB * FIPT - 1) / (FTPB * FIPT), B, 2 * FSPLIT);
        nnd_fold<<<grid, FTPB, 0, stream>>>(p1, p2, out, B, N, M);
    }
}

// Round 19
// 28.532 us; speedup vs baseline: 1.6428x; 1.2061x over previous
//
#include <hip/hip_runtime.h>

// Chamfer NN squared distances via MFMA (f16 hi/lo emulation).
// FINAL (restore of Round-11, measured 28.5us total — best of 18 rounds).
//
// d(q,r) = |q|^2 + |r|^2 - 2 q.r in ONE mfma_f32_32x32x16_f16 (13 K-slots):
//   A (query row, g=0): {-2hx,-2hy,-2hz,-2hx,-2hy,-2hz,-2lx,-2ly}
//   A (query row, g=1): {-2lz, 1, 1, sh, sl, 0, 0, 0}
//   B (ref col,   g=0): { hx,  hy,  hz,  lx,  ly,  lz, hx, hy}
//   B (ref col,   g=1): { hz,  sh,  sl,  1,  1, 0, 0, 0}
// => D = squared distance (error ~1e-4 vs 0.12 threshold).
//
// Structure: each wave owns 32 query rows (1 A-frag) and sweeps ALL refs ->
// complete min -> DIRECT STORE (single dispatch: no memset, no atomics, no
// workspace). Grid 1024 blocks (32 row-blocks x 16 batches x 2 dirs) =
// 4 blocks/CU, 4 waves/SIMD. Per chunk (512 refs, 2x16KB double-buffered
// LDS): issue next-chunk global loads (T14) -> compute buf[cur] (8 pair-
// steps: 2 ds_read_b128, 2 MFMA, 16 fmin-folds) -> pack+ds_write buf[cur^1]
// -> one barrier.
//
// Falsified alternatives (rounds 8-18): more ILP/min3 (flat), barrier-free
// L2 streaming (-8us), 8 waves/SIMD x3 (worse), SW-pipelined fold (spills),
// inline-asm min3 (miscompiles beside MFMA), pack-once+global_load_lds
// (worse), DS-halving via 2 A-frags (worse). R12 counters: issue-saturated
// (MfmaUtil 38 + VALU-only ~21%), residual is barrier-drain + MFMA-result
// latency — not addressable at HIP source level.

typedef _Float16 v8h  __attribute__((ext_vector_type(8)));
typedef float    v16f __attribute__((ext_vector_type(16)));

constexpr int TPB   = 256;        // 4 waves
constexpr int RPW   = 32;         // rows per wave (1 A-fragment)
constexpr int RPB   = 4 * RPW;    // 128 rows per block
constexpr int CHUNK = 512;        // refs per buffer (2 halves x 8 KB)

__device__ __forceinline__ void split3(float x, float y, float z,
    _Float16& hx, _Float16& hy, _Float16& hz,
    _Float16& lx, _Float16& ly, _Float16& lz,
    _Float16& sh, _Float16& sl)
{
    const float s = fmaf(z, z, fmaf(y, y, x * x));
    hx = (_Float16)x; hy = (_Float16)y; hz = (_Float16)z;
    lx = (_Float16)(x - (float)hx);
    ly = (_Float16)(y - (float)hy);
    lz = (_Float16)(z - (float)hz);
    sh = (_Float16)s;
    sl = (_Float16)(s - (float)sh);
}

__device__ __forceinline__ v8h packA(const float* __restrict__ qb, int row, int g)
{
    const float x = qb[(size_t)row * 3 + 0];
    const float y = qb[(size_t)row * 3 + 1];
    const float z = qb[(size_t)row * 3 + 2];
    _Float16 hx, hy, hz, lx, ly, lz, sh, sl;
    split3(x, y, z, hx, hy, hz, lx, ly, lz, sh, sl);
    const _Float16 nhx = (_Float16)(-2.f * x);
    const _Float16 nhy = (_Float16)(-2.f * y);
    const _Float16 nhz = (_Float16)(-2.f * z);
    const _Float16 nlx = (_Float16)(-2.f * (float)lx);
    const _Float16 nly = (_Float16)(-2.f * (float)ly);
    const _Float16 nlz = (_Float16)(-2.f * (float)lz);
    const _Float16 one = (_Float16)1.f, zz = (_Float16)0.f;
    const v8h A0 = {nhx, nhy, nhz, nhx, nhy, nhz, nlx, nly};
    const v8h A1 = {nlz, one, one, sh, sl, zz, zz, zz};
    return g ? A1 : A0;
}

__device__ __forceinline__ void packB(float x, float y, float z, uint4& h0, uint4& h1)
{
    _Float16 hx, hy, hz, lx, ly, lz, sh, sl;
    split3(x, y, z, hx, hy, hz, lx, ly, lz, sh, sl);
    const _Float16 one = (_Float16)1.f, zz = (_Float16)0.f;
    const v8h B0 = {hx, hy, hz, lx, ly, lz, hx, hy};
    const v8h B1 = {hz, sh, sl, one, one, zz, zz, zz};
    h0 = __builtin_bit_cast(uint4, B0);
    h1 = __builtin_bit_cast(uint4, B1);
}

__global__ __launch_bounds__(TPB)
__attribute__((amdgpu_waves_per_eu(4, 4)))
void nnd_mfma5(
    const float* __restrict__ p1, const float* __restrict__ p2,
    float* __restrict__ out, int B, int N, int M)
{
    const int dir = blockIdx.z;          // 0: q=p1,r=p2 (dist1); 1: swapped
    const int b   = blockIdx.y;
    const float* __restrict__ q = dir ? p2 : p1;
    const float* __restrict__ r = dir ? p1 : p2;
    const int Nq = dir ? M : N;
    const int Nr = dir ? N : M;
    float* __restrict__ o = out + (dir ? (size_t)B * N : 0) + (size_t)b * Nq;

    const int tid  = threadIdx.x;
    const int w    = tid >> 6;
    const int lane = tid & 63;
    const int c    = lane & 31;          // MFMA row (A) / col (B) within tile
    const int g    = lane >> 5;          // k-half
    const int row0 = blockIdx.x * RPB + w * RPW;

    const float* qb = q + (size_t)b * Nq * 3;
    const v8h a = packA(qb, row0 + c, g);

    v16f zc;
#pragma unroll
    for (int i = 0; i < 16; ++i) zc[i] = 0.f;
    float rm[16];
#pragma unroll
    for (int i = 0; i < 16; ++i) rm[i] = 3.0e38f;

    __shared__ uint4 sb[2][2 * CHUNK];   // [buf][half*CHUNK + slot]
    const float* rb = r + (size_t)b * Nr * 3;

    // ---- prologue: stage chunk 0 into buf 0 ----
    {
        const float2* s2 = (const float2*)rb;
        const float2 A  = s2[3 * tid + 0];
        const float2 C2 = s2[3 * tid + 1];
        const float2 E  = s2[3 * tid + 2];
        uint4 h00, h01, h10, h11;
        packB(A.x, A.y, C2.x, h00, h01);
        packB(C2.y, E.x, E.y, h10, h11);
        sb[0][tid]               = h00;
        sb[0][TPB + tid]         = h10;
        sb[0][CHUNK + tid]       = h01;
        sb[0][CHUNK + TPB + tid] = h11;
    }
    __syncthreads();

    const int NT = Nr / CHUNK;
    int cur = 0;
    for (int t = 0; t < NT; ++t) {
        const bool more = (t + 1 < NT);
        // (1) issue global loads for chunk t+1 (fly under compute)
        float2 A, C2, E;
        if (more) {
            const float2* s2 = (const float2*)(rb + (size_t)(t + 1) * CHUNK * 3);
            A  = s2[3 * tid + 0];
            C2 = s2[3 * tid + 1];
            E  = s2[3 * tid + 2];
        }
        // (2) compute on buf[cur]: 8 pair-steps (2 ds_read, 2 MFMA, 16 folds)
        const uint4* sbase = &sb[cur][g * CHUNK];
#pragma unroll 2
        for (int st = 0; st < CHUNK / 32; st += 2) {
            const v8h bfA = __builtin_bit_cast(v8h, sbase[st * 32 + c]);
            const v8h bfB = __builtin_bit_cast(v8h, sbase[st * 32 + 32 + c]);
            const v16f da = __builtin_amdgcn_mfma_f32_32x32x16_f16(a, bfA, zc, 0, 0, 0);
            const v16f db = __builtin_amdgcn_mfma_f32_32x32x16_f16(a, bfB, zc, 0, 0, 0);
#pragma unroll
            for (int i = 0; i < 16; ++i)
                rm[i] = fminf(fminf(da[i], db[i]), rm[i]);
        }
        // (3) pack + write chunk t+1 into buf[cur^1]
        if (more) {
            uint4 h00, h01, h10, h11;
            packB(A.x, A.y, C2.x, h00, h01);
            packB(C2.y, E.x, E.y, h10, h11);
            uint4* d = sb[cur ^ 1];
            d[tid]               = h00;
            d[TPB + tid]         = h10;
            d[CHUNK + tid]       = h01;
            d[CHUNK + TPB + tid] = h11;
            __syncthreads();             // writes visible before next compute
        }
        cur ^= 1;
    }

    // ---- epilogue: min over the 32 columns (bits 0-4), direct store ----
#pragma unroll
    for (int i = 0; i < 16; ++i) {
        float v = rm[i];
        v = fminf(v, __shfl_xor(v, 1));
        v = fminf(v, __shfl_xor(v, 2));
        v = fminf(v, __shfl_xor(v, 4));
        v = fminf(v, __shfl_xor(v, 8));
        v = fminf(v, __shfl_xor(v, 16));
        rm[i] = v;
    }
    if (c == 0) {
#pragma unroll
        for (int i = 0; i < 16; ++i) {
            const int rr = (i & 3) + 8 * (i >> 2) + 4 * g;  // verified C layout
            o[row0 + rr] = rm[i];
        }
    }
}

// ---------------- fallback: round-3 identity-folded VALU kernel ----------------
constexpr int FTPB   = 256;
constexpr int FIPT   = 4;
constexpr int FTILE  = 512;
constexpr int FSPLIT = 8;

__global__ __launch_bounds__(FTPB, 4) void nnd_fold(
    const float* __restrict__ p1, const float* __restrict__ p2,
    float* __restrict__ out, int B, int N, int M)
{
    const int z   = blockIdx.z;
    const int dir = z / FSPLIT;
    const int s   = z % FSPLIT;
    const int b   = blockIdx.y;

    const float* __restrict__ q = dir ? p2 : p1;
    const float* __restrict__ r = dir ? p1 : p2;
    const int Nq = dir ? M : N;
    const int Nr = dir ? N : M;
    float* __restrict__ o = out + (dir ? (size_t)B * N : 0) + (size_t)b * Nq;

    const int tid = threadIdx.x;
    const float* qb = q + (size_t)b * Nq * 3;
    float qx[FIPT], qy[FIPT], qz[FIPT], qs[FIPT], mn[FIPT];
    int   qi[FIPT];
#pragma unroll
    for (int i = 0; i < FIPT; ++i) {
        qi[i] = blockIdx.x * (FTPB * FIPT) + i * FTPB + tid;
        if (qi[i] < Nq) {
            qx[i] = qb[qi[i] * 3 + 0]; qy[i] = qb[qi[i] * 3 + 1]; qz[i] = qb[qi[i] * 3 + 2];
        } else { qx[i] = qy[i] = qz[i] = 0.f; }
        float sq = qx[i] * qx[i];
        sq = fmaf(qy[i], qy[i], sq); sq = fmaf(qz[i], qz[i], sq);
        qs[i] = sq; mn[i] = 3.0e38f;
    }
    const int per = (Nr + FSPLIT - 1) / FSPLIT;
    const int r0 = s * per, r1 = min(Nr, r0 + per);
    __shared__ float4 shm[FTILE];
    const float* rb = r + (size_t)b * Nr * 3;
    for (int ts = r0; ts < r1; ts += FTILE) {
        const int npts = min(FTILE, r1 - ts);
        __syncthreads();
        if (npts == FTILE && ((((size_t)b * Nr + (size_t)ts) * 3) & 1) == 0) {
            const float2* src = (const float2*)(rb + (size_t)ts * 3);
            float2 a = src[3 * tid + 0], c2 = src[3 * tid + 1], e = src[3 * tid + 2];
            float s0 = a.x * a.x; s0 = fmaf(a.y, a.y, s0); s0 = fmaf(c2.x, c2.x, s0);
            float s1 = c2.y * c2.y; s1 = fmaf(e.x, e.x, s1); s1 = fmaf(e.y, e.y, s1);
            shm[2 * tid + 0] = make_float4(-2.f * a.x, -2.f * a.y, -2.f * c2.x, s0);
            shm[2 * tid + 1] = make_float4(-2.f * c2.y, -2.f * e.x, -2.f * e.y, s1);
        } else {
#pragma unroll
            for (int k = 0; k < 2; ++k) {
                const int pl = 2 * tid + k;
                float4 v = make_float4(0.f, 0.f, 0.f, 3.0e38f);
                if (pl < npts) {
                    const float* pp = rb + (size_t)(ts + pl) * 3;
                    float sq = pp[0] * pp[0];
                    sq = fmaf(pp[1], pp[1], sq); sq = fmaf(pp[2], pp[2], sq);
                    v = make_float4(-2.f * pp[0], -2.f * pp[1], -2.f * pp[2], sq);
                }
                shm[pl] = v;
            }
        }
        __syncthreads();
#pragma unroll 8
        for (int j = 0; j < FTILE; ++j) {
            const float4 p = shm[j];
#pragma unroll
            for (int i = 0; i < FIPT; ++i) {
                float t = fmaf(p.x, qx[i], p.w);
                t = fmaf(p.y, qy[i], t);
                t = fmaf(p.z, qz[i], t);
                mn[i] = fminf(mn[i], t);
            }
        }
    }
#pragma unroll
    for (int i = 0; i < FIPT; ++i)
        if (qi[i] < Nq) atomicMin((int*)&o[qi[i]], __float_as_int(mn[i] + qs[i]));
}

extern "C" void kernel_launch(void* const* d_in, const int* in_sizes, int n_in,
                              void* d_out, int out_size, void* d_ws, size_t ws_size,
                              hipStream_t stream) {
    const float* p1 = (const float*)d_in[0];
    const float* p2 = (const float*)d_in[1];
    float* out = (float*)d_out;

    const int B = 16;
    const int N = in_sizes[0] / (B * 3);
    const int M = in_sizes[1] / (B * 3);

    const bool mfma_ok = (N == M) && (N % RPB == 0) && (N % CHUNK == 0);

    if (mfma_ok) {
        // single dispatch: direct stores cover every output element
        dim3 grid(N / RPB, B, 2);
        nnd_mfma5<<<grid, TPB, 0, stream>>>(p1, p2, out, B, N, M);
    } else {
        hipMemsetAsync(d_out, 0x7f, (size_t)out_size * sizeof(float), stream);
        const int qmax = (N > M) ? N : M;
        dim3 grid((qmax + FTPB * FIPT - 1) / (FTPB * FIPT), B, 2 * FSPLIT);
        nnd_fold<<<grid, FTPB, 0, stream>>>(p1, p2, out, B, N, M);
    }
}